// Round 6
// baseline (823.059 us; speedup 1.0000x reference)
//
#include <hip/hip_runtime.h>
#include <hip/hip_bf16.h>
#include <stdint.h>

// out[4096,4096] = x[4096,2048] @ matrix[0,4096,2048]^T   (fp32 in/out)
// R6: FUSED single kernel. fp32 tiles load into VGPRs (register-prefetched
// one K-iter ahead -> global latency overlaps MFMA, no barrier interaction),
// converted in-register via v_cvt_pk_bf16_f32, ds_write_b128 into the
// R2-verified XOR-swizzled bf16 LDS layout (0 conflicts). GEMM geometry =
// R2 (best measured): 128x128 tile, BK=64, 4 waves x 64x64, 4x4 frags,
// 4 blocks/CU. Eliminates the separate cvt kernel + d_ws round-trip
// (64MB rd + 32MB wr + 32MB rd of HBM traffic and one dispatch).

typedef __bf16 bf16x8 __attribute__((ext_vector_type(8)));
typedef float f32x4 __attribute__((ext_vector_type(4)));
typedef unsigned int u32x4 __attribute__((ext_vector_type(4)));

static __device__ __forceinline__ u32x4 cvt8(float4 a, float4 b) {
  union { __hip_bfloat162 h; unsigned int u; } p0, p1, p2, p3;
  p0.h = __float22bfloat162_rn(make_float2(a.x, a.y));
  p1.h = __float22bfloat162_rn(make_float2(a.z, a.w));
  p2.h = __float22bfloat162_rn(make_float2(b.x, b.y));
  p3.h = __float22bfloat162_rn(make_float2(b.z, b.w));
  u32x4 w; w[0] = p0.u; w[1] = p1.u; w[2] = p2.u; w[3] = p3.u;
  return w;
}

// C[M,N] = A[M,K]*B[N,K]^T, M=N=4096, K=2048. 256 threads = 4 waves.
// LDS: As/Bs 128 rows x 64 k bf16; elem (r,k) at r*64 + ((k>>3)^(r&7))*8 + (k&7).
__global__ __launch_bounds__(256, 4)
void gemm_fused(const float* __restrict__ A, const float* __restrict__ B,
                float* __restrict__ C) {
  constexpr int K = 2048;
  constexpr int N = 4096;

  __shared__ unsigned short As[128 * 64];   // 16 KB
  __shared__ unsigned short Bs[128 * 64];   // 16 KB

  const int tid  = threadIdx.x;
  const int wave = tid >> 6;
  const int lane = tid & 63;
  const int wm   = wave & 1;
  const int wn   = wave >> 1;
  const int bM   = blockIdx.y * 128;
  const int bN   = blockIdx.x * 128;

  const int quad = lane >> 4;
  const int l15  = lane & 15;
  const int mx   = l15 & 7;

  // Staging map: thread t covers, per group g<4, row g*32 + (t>>3),
  // k-chunk (t&7) (8 contiguous fp32). Write: one b128 per (g, tensor),
  // swizzled chunk (sc ^ (r&7)); 8 lanes/row x 16B -> all 32 banks once.
  const int sr  = tid >> 3;                 // 0..31
  const int sc  = tid & 7;                  // 0..7
  const int swz = (sc ^ (sr & 7)) << 3;
  unsigned short* const aW = As + sr * 64 + swz;
  unsigned short* const bW = Bs + sr * 64 + swz;

  const float* const Arow = A + (size_t)(bM + sr) * K + sc * 8;
  const float* const Brow = B + (size_t)(bN + sr) * K + sc * 8;

  f32x4 acc[4][4] = {};
  float4 rA[4][2], rB[4][2];   // fp32 staging registers (one K-tile)

#define LOADT(kk)                                                              \
  {                                                                            \
    _Pragma("unroll")                                                          \
    for (int g = 0; g < 4; ++g) {                                              \
      const float4* ap = (const float4*)(Arow + (size_t)g * 32 * K + (kk));    \
      const float4* bp = (const float4*)(Brow + (size_t)g * 32 * K + (kk));    \
      rA[g][0] = ap[0]; rA[g][1] = ap[1];                                      \
      rB[g][0] = bp[0]; rB[g][1] = bp[1];                                      \
    }                                                                          \
  }

  LOADT(0);

  for (int it = 0; it < K / 64; ++it) {
    __syncthreads();   // prior compute done reading LDS (WAR)
#pragma unroll
    for (int g = 0; g < 4; ++g) {
      *(u32x4*)(aW + g * 2048) = cvt8(rA[g][0], rA[g][1]);
      *(u32x4*)(bW + g * 2048) = cvt8(rB[g][0], rB[g][1]);
    }
    // prefetch next K-tile into registers; lands during compute below
    const int kn = ((it + 1) & (K / 64 - 1)) * 64;   // wraps on last iter (unused)
    LOADT(kn);
    __syncthreads();   // staged tile visible
#pragma unroll
    for (int ks = 0; ks < 2; ++ks) {
      const int koff = ((ks * 4 + quad) ^ mx) << 3;
      bf16x8 af[4], bfr[4];
#pragma unroll
      for (int i = 0; i < 4; ++i) {
        af[i]  = *(const bf16x8*)(As + (wm * 64 + i * 16 + l15) * 64 + koff);
        bfr[i] = *(const bf16x8*)(Bs + (wn * 64 + i * 16 + l15) * 64 + koff);
      }
#pragma unroll
      for (int i = 0; i < 4; ++i)
#pragma unroll
        for (int j = 0; j < 4; ++j)
          acc[i][j] = __builtin_amdgcn_mfma_f32_16x16x32_bf16(af[i], bfr[j],
                                                              acc[i][j], 0, 0, 0);
    }
  }
#undef LOADT

  // Epilogue: C/D layout col=lane&15, row=quad*4+reg (m89-verified).
#pragma unroll
  for (int i = 0; i < 4; ++i) {
    const int row0 = bM + wm * 64 + i * 16 + quad * 4;
#pragma unroll
    for (int j = 0; j < 4; ++j) {
      const int col = bN + wn * 64 + j * 16 + l15;
#pragma unroll
      for (int t = 0; t < 4; ++t)
        C[(size_t)(row0 + t) * N + col] = acc[i][j][t];
    }
  }
}

extern "C" void kernel_launch(void* const* d_in, const int* in_sizes, int n_in,
                              void* d_out, int out_size, void* d_ws, size_t ws_size,
                              hipStream_t stream) {
  const float* x   = (const float*)d_in[0];   // [4096, 2048]
  const float* mat = (const float*)d_in[1];   // [1, 4096, 2048]
  float* out = (float*)d_out;                 // [4096, 4096]

  // 1024 blocks = 4 blocks/CU on 256 CUs
  gemm_fused<<<dim3(32, 32), 256, 0, stream>>>(x, mat, out);
}